// Round 15
// baseline (125.017 us; speedup 1.0000x reference)
//
#include <hip/hip_runtime.h>
#include <stdint.h>

typedef __bf16 bf16;
typedef bf16 bf16x8 __attribute__((ext_vector_type(8)));
typedef bf16 bf16x4 __attribute__((ext_vector_type(4)));
typedef float f32x4 __attribute__((ext_vector_type(4)));
typedef float f32x16 __attribute__((ext_vector_type(16)));

#define NB 8
#define NS 1024
#define NC 512
#define NH 8
#define ND 64

// q pre-scale: dim_head^-0.5 * log2(e) so attention uses exp2 directly
#define QSCALE 0.18033688011f

__device__ __forceinline__ void gload16(const void* g, void* l) {
  __builtin_amdgcn_global_load_lds(
      (const __attribute__((address_space(1))) void*)g,
      (__attribute__((address_space(3))) void*)l, 16, 0, 0);
}

// pack two f32 -> one dword of 2 bf16 (compiler emits v_cvt_pk_bf16_f32)
__device__ __forceinline__ unsigned pk2(float lo, float hi) {
  union { bf16 h[2]; unsigned u; } c;
  c.h[0] = (bf16)lo;
  c.h[1] = (bf16)hi;
  return c.u;
}

// v_permlane32_swap_b32: x' = [x.lo | y.lo], y' = [x.hi | y.hi]
__device__ __forceinline__ void plswap(unsigned& x, unsigned& y) {
#if __has_builtin(__builtin_amdgcn_permlane32_swap)
  typedef unsigned uint2v __attribute__((ext_vector_type(2)));
  uint2v r = __builtin_amdgcn_permlane32_swap(x, y, false, false);
  x = r[0];
  y = r[1];
#else
  const bool hi = (threadIdx.x & 32) != 0;
  const unsigned xs = (unsigned)__shfl_xor((int)x, 32);
  const unsigned ys = (unsigned)__shfl_xor((int)y, 32);
  const unsigned nx = hi ? ys : x;
  const unsigned ny = hi ? y : xs;
  x = nx;
  y = ny;
#endif
}

// ---------------- 1) prep: BN+transpose (blocks 0..4095) + wconv (4096..4351)
__global__ __launch_bounds__(256) void prep_kernel(
    const float* __restrict__ x, const float* __restrict__ gam,
    const float* __restrict__ bet, const float* __restrict__ mu,
    const float* __restrict__ var, const float* __restrict__ wq,
    const float* __restrict__ wk, const float* __restrict__ wv,
    const float* __restrict__ wo, bf16* __restrict__ t, bf16* __restrict__ wqb,
    bf16* __restrict__ wkb, bf16* __restrict__ wvb, bf16* __restrict__ wob) {
  __shared__ float tile[32][33];
  const int bid = blockIdx.x;
  if (bid < 4096) {
    const int b = bid >> 9, c0 = ((bid >> 5) & 15) << 5, s0 = (bid & 31) << 5;
    const int tx = threadIdx.x, sj = tx & 31, ci = tx >> 5;
#pragma unroll
    for (int kk = 0; kk < 4; ++kk) {
      const int c = c0 + ci + (kk << 3);
      const float sc = gam[c] * rsqrtf(var[c] + 1e-5f);
      const float sh = bet[c] - mu[c] * sc;
      tile[ci + (kk << 3)][sj] = x[(size_t)(b * NC + c) * NS + s0 + sj] * sc + sh;
    }
    __syncthreads();
#pragma unroll
    for (int kk = 0; kk < 4; ++kk) {
      const int s = s0 + ci + (kk << 3);
      t[(size_t)(b * NS + s) * NC + c0 + sj] = (bf16)tile[sj][ci + (kk << 3)];
    }
  } else {
    const int i = ((bid - 4096) * 256 + threadIdx.x) * 4;
    float4 a = *(const float4*)(&wq[i]);
    float4 b = *(const float4*)(&wk[i]);
    float4 c = *(const float4*)(&wv[i]);
    float4 d = *(const float4*)(&wo[i]);
    bf16x4 av = {(bf16)a.x, (bf16)a.y, (bf16)a.z, (bf16)a.w};
    bf16x4 bv = {(bf16)b.x, (bf16)b.y, (bf16)b.z, (bf16)b.w};
    bf16x4 cv = {(bf16)c.x, (bf16)c.y, (bf16)c.z, (bf16)c.w};
    bf16x4 dv = {(bf16)d.x, (bf16)d.y, (bf16)d.z, (bf16)d.w};
    *(bf16x4*)(&wqb[i]) = av;
    *(bf16x4*)(&wkb[i]) = bv;
    *(bf16x4*)(&wvb[i]) = cv;
    *(bf16x4*)(&wob[i]) = dv;
  }
}

// ---------------- 2) QKV GEMM: 64x128 tiles, grid 1536 (6 blocks/CU) ---------
// (R13 verified; launch_bounds 4->6 raises co-residency 16->24 waves/CU)
__global__ __launch_bounds__(256, 6) void gemm_qkv_kernel(
    const bf16* __restrict__ t, const bf16* __restrict__ wqb,
    const bf16* __restrict__ wkb, const bf16* __restrict__ wvb,
    const float* __restrict__ bq, const float* __restrict__ bk,
    const float* __restrict__ bv, bf16* __restrict__ qo, bf16* __restrict__ ko,
    bf16* __restrict__ vo) {
  __shared__ __align__(16) bf16 As[2][64 * 32];   // 4KB each
  __shared__ __align__(16) bf16 Bs[2][128 * 32];  // 8KB each
  const int lid = blockIdx.x;
  const int xcd = lid & 7, rr = lid >> 3;          // rr in [0,192)
  const int ny = rr % 12, mx = (rr / 12) * 8 + xcd;  // mx in [0,128)
  const int m0 = mx << 6, n0 = ny << 7;
  const int tid = threadIdx.x;
  const int wsel = n0 >> 9;
  const bf16* W = (wsel == 0) ? wqb : (wsel == 1 ? wkb : wvb);
  const float* bias = (wsel == 0) ? bq : (wsel == 1 ? bk : bv);
  const int nb = n0 & 511;
  const int w = tid >> 6, lane = tid & 63, l15 = lane & 15, l4 = lane >> 4;
  const int wm = (w >> 1) << 5, wn = (w & 1) << 6;

  const int srl = lane >> 2, sp = lane & 3;
  const int ra = w * 16 + srl;
  const int caoff = (sp ^ ((ra >> 1) & 3)) << 3;
  const bf16* a0 = t + (size_t)(m0 + ra) * 512 + caoff;
  const int rb0 = w * 16 + srl, rb1 = 64 + w * 16 + srl;
  const int cb0off = (sp ^ ((rb0 >> 1) & 3)) << 3;
  const int cb1off = (sp ^ ((rb1 >> 1) & 3)) << 3;
  const bf16* b0 = W + (size_t)(nb + rb0) * 512 + cb0off;
  const bf16* b1 = W + (size_t)(nb + rb1) * 512 + cb1off;

  f32x4 acc[2][4] = {};
  gload16(a0, &As[0][w * 512]);
  gload16(b0, &Bs[0][w * 512]);
  gload16(b1, &Bs[0][2048 + w * 512]);
  __syncthreads();
  int buf = 0;
  for (int k0 = 0; k0 < 512; k0 += 32, buf ^= 1) {
    if (k0 + 32 < 512) {
      gload16(a0 + k0 + 32, &As[buf ^ 1][w * 512]);
      gload16(b0 + k0 + 32, &Bs[buf ^ 1][w * 512]);
      gload16(b1 + k0 + 32, &Bs[buf ^ 1][2048 + w * 512]);
    }
    bf16x8 af[2], bfv[4];
#pragma unroll
    for (int mi = 0; mi < 2; ++mi) {
      const int row = wm + mi * 16 + l15;
      af[mi] = *(const bf16x8*)(&As[buf][row * 32 + ((l4 ^ ((row >> 1) & 3)) << 3)]);
    }
#pragma unroll
    for (int ni = 0; ni < 4; ++ni) {
      const int row = wn + ni * 16 + l15;
      bfv[ni] = *(const bf16x8*)(&Bs[buf][row * 32 + ((l4 ^ ((row >> 1) & 3)) << 3)]);
    }
    if (wsel == 2) {
#pragma unroll
      for (int mi = 0; mi < 2; ++mi)
#pragma unroll
        for (int ni = 0; ni < 4; ++ni)
          acc[mi][ni] = __builtin_amdgcn_mfma_f32_16x16x32_bf16(
              af[mi], bfv[ni], acc[mi][ni], 0, 0, 0);
    } else {
#pragma unroll
      for (int mi = 0; mi < 2; ++mi)
#pragma unroll
        for (int ni = 0; ni < 4; ++ni)
          acc[mi][ni] = __builtin_amdgcn_mfma_f32_16x16x32_bf16(
              bfv[ni], af[mi], acc[mi][ni], 0, 0, 0);
    }
    __syncthreads();
  }
  const int bidx = m0 >> 10;
  if (wsel == 2) {
    const int sbase = (m0 & 1023) + wm + (l4 << 2);
#pragma unroll
    for (int ni = 0; ni < 4; ++ni) {
      const int nn = nb + wn + ni * 16 + l15;
      const int hh = nn >> 6, dd = nn & 63;
      const float bsv = bias[nn];
      bf16* vbase = vo + (size_t)(bidx * NH + hh) * (ND * NS) + (size_t)dd * NS + sbase;
#pragma unroll
      for (int mi = 0; mi < 2; ++mi) {
        bf16x4 pk;
#pragma unroll
        for (int r = 0; r < 4; ++r) pk[r] = (bf16)(acc[mi][ni][r] + bsv);
        *(bf16x4*)(&vbase[mi * 16]) = pk;
      }
    }
  } else {
    const bool isq = (wsel == 0);
    bf16* outp = isq ? qo : ko;
    const int sbase = (m0 & 1023) + wm + l15;
#pragma unroll
    for (int ni = 0; ni < 4; ++ni) {
      const int nn0 = nb + wn + ni * 16 + (l4 << 2);
      const int hh = nn0 >> 6, dd0 = nn0 & 63;
      const float4 bs4 = *(const float4*)(&bias[nn0]);
      bf16* obase = outp + (size_t)(bidx * NH + hh) * (NS * ND) + dd0;
#pragma unroll
      for (int mi = 0; mi < 2; ++mi) {
        bf16x4 pk;
        const float* bp = (const float*)&bs4;
#pragma unroll
        for (int r = 0; r < 4; ++r) {
          float val = acc[mi][ni][r] + bp[r];
          if (isq) val *= QSCALE;
          pk[r] = (bf16)val;
        }
        *(bf16x4*)(&obase[(size_t)(sbase + mi * 16) * ND]) = pk;
      }
    }
  }
}

// ---------------- 3) flash attention, 32x32 MFMA, split-KV, STATIC-SHIFT -----
// (R14 verified)
__global__ __launch_bounds__(512, 4) void attn_kernel(
    const bf16* __restrict__ qg, const bf16* __restrict__ kg,
    const bf16* __restrict__ vtg, bf16* __restrict__ og) {
  __shared__ __align__(16) bf16 KVs[2][2][2][64 * 64];  // [kvhalf][K/V][buf] 64KB
  const int lid = blockIdx.x;
  const int xcd = lid & 7, rr = lid >> 3;            // rr in [0,64)
  const int bh = ((rr & 7) << 3) + xcd;              // bh % 8 == xcd
  const int q0 = (rr >> 3) << 7;                     // q-tile * 128
  const int tid = threadIdx.x, w = tid >> 6, lane = tid & 63;
  const int wq = w & 3, wkv = w >> 2;
  const int l31 = lane & 31, hi = lane >> 5;
  const bf16* Qp = qg + ((size_t)bh * NS + q0) * ND;
  const bf16* Kp = kg + ((size_t)bh * NS + wkv * 512) * ND;
  const bf16* Vp = vtg + (size_t)bh * ND * NS + wkv * 512;

  // Q frags: lane holds Q[q=wq*32+l31][d=16ks+8hi+j]
  bf16x8 qf[4];
  {
    const bf16* qrow = Qp + (size_t)(wq * 32 + l31) * ND + hi * 8;
#pragma unroll
    for (int ks = 0; ks < 4; ++ks) qf[ks] = *(const bf16x8*)(qrow + ks * 16);
  }

  // staging: wave stages rows [wq*16, +16) of its half's K and V tiles.
  const int srow = wq * 16 + (lane >> 3);
  const int sslot = (lane & 7) ^ (srow & 7);
  const bf16* ksrc = Kp + (size_t)srow * ND + sslot * 8;
  const bf16* vsrc = Vp + (size_t)srow * NS + sslot * 8;

  f32x16 oacc0 = {}, oacc1 = {};
  float lrun = 0.f;

  gload16(ksrc, &KVs[wkv][0][0][wq * 1024]);
  gload16(ksrc + 8 * ND, &KVs[wkv][0][0][wq * 1024 + 512]);
  gload16(vsrc, &KVs[wkv][1][0][wq * 1024]);
  gload16(vsrc + 8 * NS, &KVs[wkv][1][0][wq * 1024 + 512]);
  __syncthreads();

  const int s7 = l31 & 7;  // (32+l31)&7 == l31&7
  int buf = 0;
  for (int kv0 = 0; kv0 < 512; kv0 += 64, buf ^= 1) {
    if (kv0 + 64 < 512) {
      gload16(ksrc + (size_t)(kv0 + 64) * ND, &KVs[wkv][0][buf ^ 1][wq * 1024]);
      gload16(ksrc + (size_t)(kv0 + 72) * ND,
              &KVs[wkv][0][buf ^ 1][wq * 1024 + 512]);
      gload16(vsrc + kv0 + 64, &KVs[wkv][1][buf ^ 1][wq * 1024]);
      gload16(vsrc + 8 * NS + kv0 + 64, &KVs[wkv][1][buf ^ 1][wq * 1024 + 512]);
    }
    const bf16* Ks = KVs[wkv][0][buf];
    const bf16* Vs = KVs[wkv][1][buf];
    // QK^T: C[kv][q], col=q=l31; st0 = kv 0..31 local, st1 = 32..63
    f32x16 st0 = {}, st1 = {};
    __builtin_amdgcn_s_setprio(1);
#pragma unroll
    for (int ks = 0; ks < 4; ++ks) {
      const int sl = ((2 * ks + hi) ^ s7) << 3;
      const bf16x8 a0 = *(const bf16x8*)(&Ks[l31 * 64 + sl]);
      const bf16x8 a1 = *(const bf16x8*)(&Ks[(32 + l31) * 64 + sl]);
      st0 = __builtin_amdgcn_mfma_f32_32x32x16_bf16(a0, qf[ks], st0, 0, 0, 0);
      st1 = __builtin_amdgcn_mfma_f32_32x32x16_bf16(a1, qf[ks], st1, 0, 0, 0);
    }
    __builtin_amdgcn_s_setprio(0);
    // P + PV, 16-kv ksteps; kstep t uses st[t>>1] regs [8*(t&1), +8)
    float rs = 0.f;
#pragma unroll
    for (int t = 0; t < 4; ++t) {
      float p[8];
#pragma unroll
      for (int i = 0; i < 8; ++i) {
        const float sv = (t < 2) ? st0[8 * (t & 1) + i] : st1[8 * (t & 1) + i];
        p[i] = __builtin_amdgcn_exp2f(sv);
        rs += p[i];
      }
      unsigned c01 = pk2(p[0], p[1]), c23 = pk2(p[2], p[3]);
      unsigned c45 = pk2(p[4], p[5]), c67 = pk2(p[6], p[7]);
      plswap(c01, c45);
      plswap(c23, c67);
      union { unsigned u[4]; bf16x8 v; } pu;
      pu.u[0] = c01;
      pu.u[1] = c23;
      pu.u[2] = c45;
      pu.u[3] = c67;
      const int sl = ((2 * t + hi) ^ s7) << 3;
      const bf16x8 v0 = *(const bf16x8*)(&Vs[l31 * 64 + sl]);
      const bf16x8 v1 = *(const bf16x8*)(&Vs[(32 + l31) * 64 + sl]);
      __builtin_amdgcn_s_setprio(1);
      oacc0 = __builtin_amdgcn_mfma_f32_32x32x16_bf16(v0, pu.v, oacc0, 0, 0, 0);
      oacc1 = __builtin_amdgcn_mfma_f32_32x32x16_bf16(v1, pu.v, oacc1, 0, 0, 0);
      __builtin_amdgcn_s_setprio(0);
    }
    lrun += rs;
    __syncthreads();
  }
  lrun += __shfl_xor(lrun, 32);  // full row-sum of this wave's kv half

  // cross-wave combine: upper half publishes (l, O); lower half adds + stores.
  float* comb = (float*)&KVs[0][0][0][0];
  if (wkv == 1) {
    const int base = wq * 33 * 64;
    comb[base + lane] = lrun;
#pragma unroll
    for (int i = 0; i < 16; ++i) {
      comb[base + (1 + i) * 64 + lane] = oacc0[i];
      comb[base + (17 + i) * 64 + lane] = oacc1[i];
    }
  }
  __syncthreads();
  if (wkv == 0) {
    const int base = wq * 33 * 64;
    const float lb = comb[base + lane];
    const float linv = 1.f / (lrun + lb);
    const int b = bh >> 3, h = bh & 7;
    bf16* Op = og + (size_t)(b * NS + q0 + wq * 32 + l31) * NC + h * ND;
#pragma unroll
    for (int g = 0; g < 4; ++g) {
      bf16x4 pk0, pk1;
#pragma unroll
      for (int r = 0; r < 4; ++r) {
        const float ob0 = comb[base + (1 + 4 * g + r) * 64 + lane];
        const float ob1 = comb[base + (17 + 4 * g + r) * 64 + lane];
        pk0[r] = (bf16)((oacc0[4 * g + r] + ob0) * linv);
        pk1[r] = (bf16)((oacc1[4 * g + r] + ob1) * linv);
      }
      *(bf16x4*)(&Op[g * 8 + 4 * hi]) = pk0;
      *(bf16x4*)(&Op[32 + g * 8 + 4 * hi]) = pk1;
    }
  }
}

// ---------------- 4) out GEMM: 64x64 tiles, grid 1024 (4 blocks/CU) ----------
__global__ __launch_bounds__(256, 4) void gemm_out_kernel(
    const bf16* __restrict__ wob, const bf16* __restrict__ o,
    const float* __restrict__ bo, float* __restrict__ out) {
  __shared__ __align__(16) bf16 As[2][64 * 32];  // 4KB each
  __shared__ __align__(16) bf16 Bs[2][64 * 32];
  const int lid = blockIdx.x;
  const int xcd = lid & 7, rr = lid >> 3;              // rr in [0,128)
  const int mx = rr & 7, ny = ((rr >> 3) << 3) + xcd;  // same-ny 8x on one XCD
  const int m0 = mx << 6, n0 = ny << 6;
  const int tid = threadIdx.x;
  const int w = tid >> 6, lane = tid & 63, l15 = lane & 15, l4 = lane >> 4;
  const int wm = (w >> 1) << 5;  // cout offset 0/32
  const int wn = (w & 1) << 5;   // s offset 0/32

  const int srow = tid >> 2, sp = tid & 3;  // 64 rows x 4 slots
  const int coff = (sp ^ ((srow >> 1) & 3)) << 3;
  const bf16* a0 = wob + (size_t)(m0 + srow) * 512 + coff;
  const bf16* b0 = o + (size_t)(n0 + srow) * 512 + coff;

  f32x4 acc[2][2] = {};
  gload16(a0, &As[0][w * 512]);
  gload16(b0, &Bs[0][w * 512]);
  __syncthreads();
  int buf = 0;
  for (int k0 = 0; k0 < 512; k0 += 32, buf ^= 1) {
    if (k0 + 32 < 512) {
      gload16(a0 + k0 + 32, &As[buf ^ 1][w * 512]);
      gload16(b0 + k0 + 32, &Bs[buf ^ 1][w * 512]);
    }
    bf16x8 af[2], bfv[2];
#pragma unroll
    for (int mi = 0; mi < 2; ++mi) {
      const int row = wm + mi * 16 + l15;
      af[mi] = *(const bf16x8*)(&As[buf][row * 32 + ((l4 ^ ((row >> 1) & 3)) << 3)]);
    }
#pragma unroll
    for (int ni = 0; ni < 2; ++ni) {
      const int row = wn + ni * 16 + l15;
      bfv[ni] = *(const bf16x8*)(&Bs[buf][row * 32 + ((l4 ^ ((row >> 1) & 3)) << 3)]);
    }
#pragma unroll
    for (int mi = 0; mi < 2; ++mi)
#pragma unroll
      for (int ni = 0; ni < 2; ++ni)
        acc[mi][ni] = __builtin_amdgcn_mfma_f32_16x16x32_bf16(
            bfv[ni], af[mi], acc[mi][ni], 0, 0, 0);
    __syncthreads();
  }
  const int b = n0 >> 10;
  const int sb = (n0 & 1023) + wn;
#pragma unroll
  for (int mi = 0; mi < 2; ++mi) {
    const int cout = m0 + wm + mi * 16 + l15;
    const float bsv = bo[cout];
    float* obase = out + (size_t)(b * NC + cout) * NS;
#pragma unroll
    for (int ni = 0; ni < 2; ++ni) {
      const int s0i = sb + ni * 16 + (l4 << 2);
      float4 pk = {acc[mi][ni][0] + bsv, acc[mi][ni][1] + bsv,
                   acc[mi][ni][2] + bsv, acc[mi][ni][3] + bsv};
      *(float4*)(&obase[s0i]) = pk;
    }
  }
}

// ---------------- launcher --------------------------------------------------
extern "C" void kernel_launch(void* const* d_in, const int* in_sizes, int n_in,
                              void* d_out, int out_size, void* d_ws,
                              size_t ws_size, hipStream_t stream) {
  const float* x = (const float*)d_in[0];
  const float* gam = (const float*)d_in[1];
  const float* bet = (const float*)d_in[2];
  const float* mu = (const float*)d_in[3];
  const float* var = (const float*)d_in[4];
  const float* wq = (const float*)d_in[5];
  const float* bq = (const float*)d_in[6];
  const float* wk = (const float*)d_in[7];
  const float* bk = (const float*)d_in[8];
  const float* wv = (const float*)d_in[9];
  const float* bv = (const float*)d_in[10];
  const float* wo = (const float*)d_in[11];
  const float* bo = (const float*)d_in[12];
  float* out = (float*)d_out;

  char* p = (char*)d_ws;
  const size_t big = (size_t)8192 * 512 * sizeof(bf16);  // 8.39 MB
  bf16* t = (bf16*)p;   p += big;  // reused as attention output o
  bf16* q = (bf16*)p;   p += big;
  bf16* k = (bf16*)p;   p += big;
  bf16* vt = (bf16*)p;  p += big;  // V already transposed [B][H][D][S]
  const size_t wsz = (size_t)512 * 512 * sizeof(bf16);
  bf16* wqb = (bf16*)p; p += wsz;
  bf16* wkb = (bf16*)p; p += wsz;
  bf16* wvb = (bf16*)p; p += wsz;
  bf16* wob = (bf16*)p; p += wsz;
  bf16* o = t;

  prep_kernel<<<dim3(4352), 256, 0, stream>>>(x, gam, bet, mu, var, wq, wk, wv,
                                              wo, t, wqb, wkb, wvb, wob);
  gemm_qkv_kernel<<<dim3(1536), 256, 0, stream>>>(t, wqb, wkb, wvb, bq, bk, bv,
                                                  q, k, vt);
  attn_kernel<<<dim3(512), 512, 0, stream>>>(q, k, vt, o);
  gemm_out_kernel<<<dim3(1024), 256, 0, stream>>>(wob, o, bo, out);
}

// Round 16
// 76.523 us; speedup vs baseline: 1.6337x; 1.6337x over previous
//
#include <hip/hip_runtime.h>
#include <stdint.h>

typedef __bf16 bf16;
typedef bf16 bf16x8 __attribute__((ext_vector_type(8)));
typedef bf16 bf16x4 __attribute__((ext_vector_type(4)));
typedef float f32x4 __attribute__((ext_vector_type(4)));
typedef float f32x16 __attribute__((ext_vector_type(16)));

#define NB 8
#define NS 1024
#define NC 512
#define NH 8
#define ND 64

// q pre-scale: dim_head^-0.5 * log2(e) so attention uses exp2 directly
#define QSCALE 0.18033688011f

__device__ __forceinline__ void gload16(const void* g, void* l) {
  __builtin_amdgcn_global_load_lds(
      (const __attribute__((address_space(1))) void*)g,
      (__attribute__((address_space(3))) void*)l, 16, 0, 0);
}

// pack two f32 -> one dword of 2 bf16 (compiler emits v_cvt_pk_bf16_f32)
__device__ __forceinline__ unsigned pk2(float lo, float hi) {
  union { bf16 h[2]; unsigned u; } c;
  c.h[0] = (bf16)lo;
  c.h[1] = (bf16)hi;
  return c.u;
}

// v_permlane32_swap_b32: x' = [x.lo | y.lo], y' = [x.hi | y.hi]
__device__ __forceinline__ void plswap(unsigned& x, unsigned& y) {
#if __has_builtin(__builtin_amdgcn_permlane32_swap)
  typedef unsigned uint2v __attribute__((ext_vector_type(2)));
  uint2v r = __builtin_amdgcn_permlane32_swap(x, y, false, false);
  x = r[0];
  y = r[1];
#else
  const bool hi = (threadIdx.x & 32) != 0;
  const unsigned xs = (unsigned)__shfl_xor((int)x, 32);
  const unsigned ys = (unsigned)__shfl_xor((int)y, 32);
  const unsigned nx = hi ? ys : x;
  const unsigned ny = hi ? y : xs;
  x = nx;
  y = ny;
#endif
}

// ---------------- 1) prep: BN+transpose (blocks 0..4095) + wconv (4096..4351)
__global__ __launch_bounds__(256) void prep_kernel(
    const float* __restrict__ x, const float* __restrict__ gam,
    const float* __restrict__ bet, const float* __restrict__ mu,
    const float* __restrict__ var, const float* __restrict__ wq,
    const float* __restrict__ wk, const float* __restrict__ wv,
    const float* __restrict__ wo, bf16* __restrict__ t, bf16* __restrict__ wqb,
    bf16* __restrict__ wkb, bf16* __restrict__ wvb, bf16* __restrict__ wob) {
  __shared__ float tile[32][33];
  const int bid = blockIdx.x;
  if (bid < 4096) {
    const int b = bid >> 9, c0 = ((bid >> 5) & 15) << 5, s0 = (bid & 31) << 5;
    const int tx = threadIdx.x, sj = tx & 31, ci = tx >> 5;
#pragma unroll
    for (int kk = 0; kk < 4; ++kk) {
      const int c = c0 + ci + (kk << 3);
      const float sc = gam[c] * rsqrtf(var[c] + 1e-5f);
      const float sh = bet[c] - mu[c] * sc;
      tile[ci + (kk << 3)][sj] = x[(size_t)(b * NC + c) * NS + s0 + sj] * sc + sh;
    }
    __syncthreads();
#pragma unroll
    for (int kk = 0; kk < 4; ++kk) {
      const int s = s0 + ci + (kk << 3);
      t[(size_t)(b * NS + s) * NC + c0 + sj] = (bf16)tile[sj][ci + (kk << 3)];
    }
  } else {
    const int i = ((bid - 4096) * 256 + threadIdx.x) * 4;
    float4 a = *(const float4*)(&wq[i]);
    float4 b = *(const float4*)(&wk[i]);
    float4 c = *(const float4*)(&wv[i]);
    float4 d = *(const float4*)(&wo[i]);
    bf16x4 av = {(bf16)a.x, (bf16)a.y, (bf16)a.z, (bf16)a.w};
    bf16x4 bv = {(bf16)b.x, (bf16)b.y, (bf16)b.z, (bf16)b.w};
    bf16x4 cv = {(bf16)c.x, (bf16)c.y, (bf16)c.z, (bf16)c.w};
    bf16x4 dv = {(bf16)d.x, (bf16)d.y, (bf16)d.z, (bf16)d.w};
    *(bf16x4*)(&wqb[i]) = av;
    *(bf16x4*)(&wkb[i]) = bv;
    *(bf16x4*)(&wvb[i]) = cv;
    *(bf16x4*)(&wob[i]) = dv;
  }
}

// ---------------- 2) QKV GEMM: 64x128 tiles, grid 1536 (4 blocks/CU) ---------
// (R13 verified; bounds (256,4) — (256,6) caused a total spill collapse, R15)
__global__ __launch_bounds__(256, 4) void gemm_qkv_kernel(
    const bf16* __restrict__ t, const bf16* __restrict__ wqb,
    const bf16* __restrict__ wkb, const bf16* __restrict__ wvb,
    const float* __restrict__ bq, const float* __restrict__ bk,
    const float* __restrict__ bv, bf16* __restrict__ qo, bf16* __restrict__ ko,
    bf16* __restrict__ vo) {
  __shared__ __align__(16) bf16 As[2][64 * 32];   // 4KB each
  __shared__ __align__(16) bf16 Bs[2][128 * 32];  // 8KB each
  const int lid = blockIdx.x;
  const int xcd = lid & 7, rr = lid >> 3;          // rr in [0,192)
  const int ny = rr % 12, mx = (rr / 12) * 8 + xcd;  // mx in [0,128)
  const int m0 = mx << 6, n0 = ny << 7;
  const int tid = threadIdx.x;
  const int wsel = n0 >> 9;
  const bf16* W = (wsel == 0) ? wqb : (wsel == 1 ? wkb : wvb);
  const float* bias = (wsel == 0) ? bq : (wsel == 1 ? bk : bv);
  const int nb = n0 & 511;
  const int w = tid >> 6, lane = tid & 63, l15 = lane & 15, l4 = lane >> 4;
  const int wm = (w >> 1) << 5, wn = (w & 1) << 6;

  const int srl = lane >> 2, sp = lane & 3;
  const int ra = w * 16 + srl;
  const int caoff = (sp ^ ((ra >> 1) & 3)) << 3;
  const bf16* a0 = t + (size_t)(m0 + ra) * 512 + caoff;
  const int rb0 = w * 16 + srl, rb1 = 64 + w * 16 + srl;
  const int cb0off = (sp ^ ((rb0 >> 1) & 3)) << 3;
  const int cb1off = (sp ^ ((rb1 >> 1) & 3)) << 3;
  const bf16* b0 = W + (size_t)(nb + rb0) * 512 + cb0off;
  const bf16* b1 = W + (size_t)(nb + rb1) * 512 + cb1off;

  f32x4 acc[2][4] = {};
  gload16(a0, &As[0][w * 512]);
  gload16(b0, &Bs[0][w * 512]);
  gload16(b1, &Bs[0][2048 + w * 512]);
  __syncthreads();
  int buf = 0;
  for (int k0 = 0; k0 < 512; k0 += 32, buf ^= 1) {
    if (k0 + 32 < 512) {
      gload16(a0 + k0 + 32, &As[buf ^ 1][w * 512]);
      gload16(b0 + k0 + 32, &Bs[buf ^ 1][w * 512]);
      gload16(b1 + k0 + 32, &Bs[buf ^ 1][2048 + w * 512]);
    }
    bf16x8 af[2], bfv[4];
#pragma unroll
    for (int mi = 0; mi < 2; ++mi) {
      const int row = wm + mi * 16 + l15;
      af[mi] = *(const bf16x8*)(&As[buf][row * 32 + ((l4 ^ ((row >> 1) & 3)) << 3)]);
    }
#pragma unroll
    for (int ni = 0; ni < 4; ++ni) {
      const int row = wn + ni * 16 + l15;
      bfv[ni] = *(const bf16x8*)(&Bs[buf][row * 32 + ((l4 ^ ((row >> 1) & 3)) << 3)]);
    }
    if (wsel == 2) {
#pragma unroll
      for (int mi = 0; mi < 2; ++mi)
#pragma unroll
        for (int ni = 0; ni < 4; ++ni)
          acc[mi][ni] = __builtin_amdgcn_mfma_f32_16x16x32_bf16(
              af[mi], bfv[ni], acc[mi][ni], 0, 0, 0);
    } else {
#pragma unroll
      for (int mi = 0; mi < 2; ++mi)
#pragma unroll
        for (int ni = 0; ni < 4; ++ni)
          acc[mi][ni] = __builtin_amdgcn_mfma_f32_16x16x32_bf16(
              bfv[ni], af[mi], acc[mi][ni], 0, 0, 0);
    }
    __syncthreads();
  }
  const int bidx = m0 >> 10;
  if (wsel == 2) {
    const int sbase = (m0 & 1023) + wm + (l4 << 2);
#pragma unroll
    for (int ni = 0; ni < 4; ++ni) {
      const int nn = nb + wn + ni * 16 + l15;
      const int hh = nn >> 6, dd = nn & 63;
      const float bsv = bias[nn];
      bf16* vbase = vo + (size_t)(bidx * NH + hh) * (ND * NS) + (size_t)dd * NS + sbase;
#pragma unroll
      for (int mi = 0; mi < 2; ++mi) {
        bf16x4 pk;
#pragma unroll
        for (int r = 0; r < 4; ++r) pk[r] = (bf16)(acc[mi][ni][r] + bsv);
        *(bf16x4*)(&vbase[mi * 16]) = pk;
      }
    }
  } else {
    const bool isq = (wsel == 0);
    bf16* outp = isq ? qo : ko;
    const int sbase = (m0 & 1023) + wm + l15;
#pragma unroll
    for (int ni = 0; ni < 4; ++ni) {
      const int nn0 = nb + wn + ni * 16 + (l4 << 2);
      const int hh = nn0 >> 6, dd0 = nn0 & 63;
      const float4 bs4 = *(const float4*)(&bias[nn0]);
      bf16* obase = outp + (size_t)(bidx * NH + hh) * (NS * ND) + dd0;
#pragma unroll
      for (int mi = 0; mi < 2; ++mi) {
        bf16x4 pk;
        const float* bp = (const float*)&bs4;
#pragma unroll
        for (int r = 0; r < 4; ++r) {
          float val = acc[mi][ni][r] + bp[r];
          if (isq) val *= QSCALE;
          pk[r] = (bf16)val;
        }
        *(bf16x4*)(&obase[(size_t)(sbase + mi * 16) * ND]) = pk;
      }
    }
  }
}

// ---------------- 3) flash attention, 32x32 MFMA, split-KV, STATIC-SHIFT -----
// (R14 verified)
__global__ __launch_bounds__(512, 4) void attn_kernel(
    const bf16* __restrict__ qg, const bf16* __restrict__ kg,
    const bf16* __restrict__ vtg, bf16* __restrict__ og) {
  __shared__ __align__(16) bf16 KVs[2][2][2][64 * 64];  // [kvhalf][K/V][buf] 64KB
  const int lid = blockIdx.x;
  const int xcd = lid & 7, rr = lid >> 3;            // rr in [0,64)
  const int bh = ((rr & 7) << 3) + xcd;              // bh % 8 == xcd
  const int q0 = (rr >> 3) << 7;                     // q-tile * 128
  const int tid = threadIdx.x, w = tid >> 6, lane = tid & 63;
  const int wq = w & 3, wkv = w >> 2;
  const int l31 = lane & 31, hi = lane >> 5;
  const bf16* Qp = qg + ((size_t)bh * NS + q0) * ND;
  const bf16* Kp = kg + ((size_t)bh * NS + wkv * 512) * ND;
  const bf16* Vp = vtg + (size_t)bh * ND * NS + wkv * 512;

  // Q frags: lane holds Q[q=wq*32+l31][d=16ks+8hi+j]
  bf16x8 qf[4];
  {
    const bf16* qrow = Qp + (size_t)(wq * 32 + l31) * ND + hi * 8;
#pragma unroll
    for (int ks = 0; ks < 4; ++ks) qf[ks] = *(const bf16x8*)(qrow + ks * 16);
  }

  // staging: wave stages rows [wq*16, +16) of its half's K and V tiles.
  const int srow = wq * 16 + (lane >> 3);
  const int sslot = (lane & 7) ^ (srow & 7);
  const bf16* ksrc = Kp + (size_t)srow * ND + sslot * 8;
  const bf16* vsrc = Vp + (size_t)srow * NS + sslot * 8;

  f32x16 oacc0 = {}, oacc1 = {};
  float lrun = 0.f;

  gload16(ksrc, &KVs[wkv][0][0][wq * 1024]);
  gload16(ksrc + 8 * ND, &KVs[wkv][0][0][wq * 1024 + 512]);
  gload16(vsrc, &KVs[wkv][1][0][wq * 1024]);
  gload16(vsrc + 8 * NS, &KVs[wkv][1][0][wq * 1024 + 512]);
  __syncthreads();

  const int s7 = l31 & 7;  // (32+l31)&7 == l31&7
  int buf = 0;
  for (int kv0 = 0; kv0 < 512; kv0 += 64, buf ^= 1) {
    if (kv0 + 64 < 512) {
      gload16(ksrc + (size_t)(kv0 + 64) * ND, &KVs[wkv][0][buf ^ 1][wq * 1024]);
      gload16(ksrc + (size_t)(kv0 + 72) * ND,
              &KVs[wkv][0][buf ^ 1][wq * 1024 + 512]);
      gload16(vsrc + kv0 + 64, &KVs[wkv][1][buf ^ 1][wq * 1024]);
      gload16(vsrc + 8 * NS + kv0 + 64, &KVs[wkv][1][buf ^ 1][wq * 1024 + 512]);
    }
    const bf16* Ks = KVs[wkv][0][buf];
    const bf16* Vs = KVs[wkv][1][buf];
    // QK^T: C[kv][q], col=q=l31; st0 = kv 0..31 local, st1 = 32..63
    f32x16 st0 = {}, st1 = {};
    __builtin_amdgcn_s_setprio(1);
#pragma unroll
    for (int ks = 0; ks < 4; ++ks) {
      const int sl = ((2 * ks + hi) ^ s7) << 3;
      const bf16x8 a0 = *(const bf16x8*)(&Ks[l31 * 64 + sl]);
      const bf16x8 a1 = *(const bf16x8*)(&Ks[(32 + l31) * 64 + sl]);
      st0 = __builtin_amdgcn_mfma_f32_32x32x16_bf16(a0, qf[ks], st0, 0, 0, 0);
      st1 = __builtin_amdgcn_mfma_f32_32x32x16_bf16(a1, qf[ks], st1, 0, 0, 0);
    }
    __builtin_amdgcn_s_setprio(0);
    // P + PV, 16-kv ksteps; kstep t uses st[t>>1] regs [8*(t&1), +8)
    float rs = 0.f;
#pragma unroll
    for (int t = 0; t < 4; ++t) {
      float p[8];
#pragma unroll
      for (int i = 0; i < 8; ++i) {
        const float sv = (t < 2) ? st0[8 * (t & 1) + i] : st1[8 * (t & 1) + i];
        p[i] = __builtin_amdgcn_exp2f(sv);
        rs += p[i];
      }
      unsigned c01 = pk2(p[0], p[1]), c23 = pk2(p[2], p[3]);
      unsigned c45 = pk2(p[4], p[5]), c67 = pk2(p[6], p[7]);
      plswap(c01, c45);
      plswap(c23, c67);
      union { unsigned u[4]; bf16x8 v; } pu;
      pu.u[0] = c01;
      pu.u[1] = c23;
      pu.u[2] = c45;
      pu.u[3] = c67;
      const int sl = ((2 * t + hi) ^ s7) << 3;
      const bf16x8 v0 = *(const bf16x8*)(&Vs[l31 * 64 + sl]);
      const bf16x8 v1 = *(const bf16x8*)(&Vs[(32 + l31) * 64 + sl]);
      __builtin_amdgcn_s_setprio(1);
      oacc0 = __builtin_amdgcn_mfma_f32_32x32x16_bf16(v0, pu.v, oacc0, 0, 0, 0);
      oacc1 = __builtin_amdgcn_mfma_f32_32x32x16_bf16(v1, pu.v, oacc1, 0, 0, 0);
      __builtin_amdgcn_s_setprio(0);
    }
    lrun += rs;
    __syncthreads();
  }
  lrun += __shfl_xor(lrun, 32);  // full row-sum of this wave's kv half

  // cross-wave combine: upper half publishes (l, O); lower half adds + stores.
  float* comb = (float*)&KVs[0][0][0][0];
  if (wkv == 1) {
    const int base = wq * 33 * 64;
    comb[base + lane] = lrun;
#pragma unroll
    for (int i = 0; i < 16; ++i) {
      comb[base + (1 + i) * 64 + lane] = oacc0[i];
      comb[base + (17 + i) * 64 + lane] = oacc1[i];
    }
  }
  __syncthreads();
  if (wkv == 0) {
    const int base = wq * 33 * 64;
    const float lb = comb[base + lane];
    const float linv = 1.f / (lrun + lb);
    const int b = bh >> 3, h = bh & 7;
    bf16* Op = og + (size_t)(b * NS + q0 + wq * 32 + l31) * NC + h * ND;
#pragma unroll
    for (int g = 0; g < 4; ++g) {
      bf16x4 pk0, pk1;
#pragma unroll
      for (int r = 0; r < 4; ++r) {
        const float ob0 = comb[base + (1 + 4 * g + r) * 64 + lane];
        const float ob1 = comb[base + (17 + 4 * g + r) * 64 + lane];
        pk0[r] = (bf16)((oacc0[4 * g + r] + ob0) * linv);
        pk1[r] = (bf16)((oacc1[4 * g + r] + ob1) * linv);
      }
      *(bf16x4*)(&Op[g * 8 + 4 * hi]) = pk0;
      *(bf16x4*)(&Op[32 + g * 8 + 4 * hi]) = pk1;
    }
  }
}

// ---------------- 4) out GEMM: 64x64 tiles, grid 1024 (4 blocks/CU) ----------
__global__ __launch_bounds__(256, 4) void gemm_out_kernel(
    const bf16* __restrict__ wob, const bf16* __restrict__ o,
    const float* __restrict__ bo, float* __restrict__ out) {
  __shared__ __align__(16) bf16 As[2][64 * 32];  // 4KB each
  __shared__ __align__(16) bf16 Bs[2][64 * 32];
  const int lid = blockIdx.x;
  const int xcd = lid & 7, rr = lid >> 3;              // rr in [0,128)
  const int mx = rr & 7, ny = ((rr >> 3) << 3) + xcd;  // same-ny 8x on one XCD
  const int m0 = mx << 6, n0 = ny << 6;
  const int tid = threadIdx.x;
  const int w = tid >> 6, lane = tid & 63, l15 = lane & 15, l4 = lane >> 4;
  const int wm = (w >> 1) << 5;  // cout offset 0/32
  const int wn = (w & 1) << 5;   // s offset 0/32

  const int srow = tid >> 2, sp = tid & 3;  // 64 rows x 4 slots
  const int coff = (sp ^ ((srow >> 1) & 3)) << 3;
  const bf16* a0 = wob + (size_t)(m0 + srow) * 512 + coff;
  const bf16* b0 = o + (size_t)(n0 + srow) * 512 + coff;

  f32x4 acc[2][2] = {};
  gload16(a0, &As[0][w * 512]);
  gload16(b0, &Bs[0][w * 512]);
  __syncthreads();
  int buf = 0;
  for (int k0 = 0; k0 < 512; k0 += 32, buf ^= 1) {
    if (k0 + 32 < 512) {
      gload16(a0 + k0 + 32, &As[buf ^ 1][w * 512]);
      gload16(b0 + k0 + 32, &Bs[buf ^ 1][w * 512]);
    }
    bf16x8 af[2], bfv[2];
#pragma unroll
    for (int mi = 0; mi < 2; ++mi) {
      const int row = wm + mi * 16 + l15;
      af[mi] = *(const bf16x8*)(&As[buf][row * 32 + ((l4 ^ ((row >> 1) & 3)) << 3)]);
    }
#pragma unroll
    for (int ni = 0; ni < 2; ++ni) {
      const int row = wn + ni * 16 + l15;
      bfv[ni] = *(const bf16x8*)(&Bs[buf][row * 32 + ((l4 ^ ((row >> 1) & 3)) << 3)]);
    }
#pragma unroll
    for (int mi = 0; mi < 2; ++mi)
#pragma unroll
      for (int ni = 0; ni < 2; ++ni)
        acc[mi][ni] = __builtin_amdgcn_mfma_f32_16x16x32_bf16(
            bfv[ni], af[mi], acc[mi][ni], 0, 0, 0);
    __syncthreads();
  }
  const int b = n0 >> 10;
  const int sb = (n0 & 1023) + wn;
#pragma unroll
  for (int mi = 0; mi < 2; ++mi) {
    const int cout = m0 + wm + mi * 16 + l15;
    const float bsv = bo[cout];
    float* obase = out + (size_t)(b * NC + cout) * NS;
#pragma unroll
    for (int ni = 0; ni < 2; ++ni) {
      const int s0i = sb + ni * 16 + (l4 << 2);
      float4 pk = {acc[mi][ni][0] + bsv, acc[mi][ni][1] + bsv,
                   acc[mi][ni][2] + bsv, acc[mi][ni][3] + bsv};
      *(float4*)(&obase[s0i]) = pk;
    }
  }
}

// ---------------- launcher --------------------------------------------------
extern "C" void kernel_launch(void* const* d_in, const int* in_sizes, int n_in,
                              void* d_out, int out_size, void* d_ws,
                              size_t ws_size, hipStream_t stream) {
  const float* x = (const float*)d_in[0];
  const float* gam = (const float*)d_in[1];
  const float* bet = (const float*)d_in[2];
  const float* mu = (const float*)d_in[3];
  const float* var = (const float*)d_in[4];
  const float* wq = (const float*)d_in[5];
  const float* bq = (const float*)d_in[6];
  const float* wk = (const float*)d_in[7];
  const float* bk = (const float*)d_in[8];
  const float* wv = (const float*)d_in[9];
  const float* bv = (const float*)d_in[10];
  const float* wo = (const float*)d_in[11];
  const float* bo = (const float*)d_in[12];
  float* out = (float*)d_out;

  char* p = (char*)d_ws;
  const size_t big = (size_t)8192 * 512 * sizeof(bf16);  // 8.39 MB
  bf16* t = (bf16*)p;   p += big;  // reused as attention output o
  bf16* q = (bf16*)p;   p += big;
  bf16* k = (bf16*)p;   p += big;
  bf16* vt = (bf16*)p;  p += big;  // V already transposed [B][H][D][S]
  const size_t wsz = (size_t)512 * 512 * sizeof(bf16);
  bf16* wqb = (bf16*)p; p += wsz;
  bf16* wkb = (bf16*)p; p += wsz;
  bf16* wvb = (bf16*)p; p += wsz;
  bf16* wob = (bf16*)p; p += wsz;
  bf16* o = t;

  prep_kernel<<<dim3(4352), 256, 0, stream>>>(x, gam, bet, mu, var, wq, wk, wv,
                                              wo, t, wqb, wkb, wvb, wob);
  gemm_qkv_kernel<<<dim3(1536), 256, 0, stream>>>(t, wqb, wkb, wvb, bq, bk, bv,
                                                  q, k, vt);
  attn_kernel<<<dim3(512), 512, 0, stream>>>(q, k, vt, o);
  gemm_out_kernel<<<dim3(1024), 256, 0, stream>>>(wob, o, bo, out);
}